// Round 1
// baseline (738.146 us; speedup 1.0000x reference)
//
#include <hip/hip_runtime.h>
#include <hip/hip_bf16.h>

#define TT 36
#define FF 18
#define HH 128
#define BB 16
#define BLOCK 512

typedef __attribute__((ext_vector_type(4))) float f32x4;
typedef __attribute__((ext_vector_type(8))) short bf16x8;

static __device__ __forceinline__ float bf2f(unsigned short u) {
    unsigned int x = ((unsigned int)u) << 16;
    return __builtin_bit_cast(float, x);
}
static __device__ __forceinline__ unsigned short f2bf(float f) {
    unsigned int x = __builtin_bit_cast(unsigned int, f);
    unsigned int r = (x + 0x7fffu + ((x >> 16) & 1u)) >> 16;
    return (unsigned short)r;
}
static __device__ __forceinline__ float tanh_fast(float x) {
    return 1.f - 2.f / (1.f + __expf(2.f * x));
}
static __device__ __forceinline__ float sigmoid_fast(float x) {
    return 1.f / (1.f + __expf(-x));
}
static __device__ __forceinline__ f32x4 mfma16(bf16x8 a, bf16x8 b, f32x4 c) {
    return __builtin_amdgcn_mfma_f32_16x16x32_bf16(a, b, c, 0, 0, 0);
}

__global__ __launch_bounds__(BLOCK) void enc_att_gru(
    const float* __restrict__ seqs, const float* __restrict__ mask,
    const float* __restrict__ Wh,   const float* __restrict__ bh,
    const float* __restrict__ Ws,   const float* __restrict__ bs,
    const float* __restrict__ Wo,   const float* __restrict__ bo,
    const float* __restrict__ W_ih, const float* __restrict__ W_hh,
    const float* __restrict__ b_ih, const float* __restrict__ b_hh,
    float* __restrict__ out)
{
    __shared__ unsigned short seq_lds[BB][TT * FF];   // bf16 seqs tile
    __shared__ unsigned short sig_lds[BB][FF * TT];   // bf16 lin_signal [bb][f*36+t]
    __shared__ unsigned short h_lds[BB][HH];          // bf16 hidden, XOR-swizzled rows
    __shared__ unsigned short x_lds[BB][32];          // bf16 attention-scaled input, padded K
    __shared__ float linh_lds[BB][48];
    __shared__ float e_lds[BB][FF];
    __shared__ float mask_lds[BB][TT];
    __shared__ float Ws_lds[TT][TT];
    __shared__ float wo_lds[TT];
    __shared__ float bs_lds[TT];

    const int tid  = threadIdx.x;
    const int wave = tid >> 6;
    const int lane = tid & 63;
    const int l15  = lane & 15;
    const int l4   = lane >> 4;          // 0..3
    const int bbase = blockIdx.x * BB;

    // ---- stage seqs (coalesced) -> bf16 LDS ----
    for (int idx = tid; idx < BB * TT * FF; idx += BLOCK) {
        int bb = idx / (TT * FF);
        int r  = idx - bb * (TT * FF);
        seq_lds[bb][r] = f2bf(seqs[(size_t)(bbase + bb) * (TT * FF) + r]);
    }
    for (int idx = tid; idx < BB * TT; idx += BLOCK) {
        int bb = idx / TT, t = idx - bb * TT;
        mask_lds[bb][t] = mask[(size_t)(bbase + bb) * TT + t];
    }
    for (int idx = tid; idx < TT * TT; idx += BLOCK)
        Ws_lds[idx / TT][idx % TT] = Ws[idx];
    if (tid < TT) { wo_lds[tid] = Wo[tid]; bs_lds[tid] = bs[tid]; }
    for (int idx = tid; idx < BB * HH; idx += BLOCK) ((unsigned short*)h_lds)[idx] = 0;
    for (int idx = tid; idx < BB * 32; idx += BLOCK) ((unsigned short*)x_lds)[idx] = 0;

    // ---- persistent weight fragments in registers ----
    // B-frag convention: elem j of lane l is  B[k = kt*32 + (l>>4)*8 + j][n = ntile*16 + (l&15)]
    // Same k-mapping used for A-frags, so any error in the k-permutation cancels.
    bf16x8 whh[3][4];   // gh:   n = g*128 + 16*wave + l15, k over 128
    for (int g = 0; g < 3; ++g)
        for (int kt = 0; kt < 4; ++kt) {
            const int o = g * HH + 16 * wave + l15;
            bf16x8 fr;
#pragma unroll
            for (int jj = 0; jj < 8; ++jj) {
                int k = kt * 32 + l4 * 8 + jj;
                fr[jj] = (short)f2bf(W_hh[(size_t)o * HH + k]);
            }
            whh[g][kt] = fr;
        }
    bf16x8 wih[3];      // gi: K = F padded to 32
    for (int g = 0; g < 3; ++g) {
        const int o = g * HH + 16 * wave + l15;
        bf16x8 fr;
#pragma unroll
        for (int jj = 0; jj < 8; ++jj) {
            int f = l4 * 8 + jj;
            fr[jj] = (f < FF) ? (short)f2bf(W_ih[(size_t)o * FF + f]) : (short)0;
        }
        wih[g] = fr;
    }
    const int tcol = 16 * wave + l15;    // lin_h output column (t), waves 0..2
    bf16x8 whf[4];      // lin_h: n = t (padded to 48), k over 128
    for (int kt = 0; kt < 4; ++kt) {
        bf16x8 fr;
#pragma unroll
        for (int jj = 0; jj < 8; ++jj) {
            int k = kt * 32 + l4 * 8 + jj;
            fr[jj] = (wave < 3 && tcol < TT) ? (short)f2bf(Wh[(size_t)tcol * HH + k]) : (short)0;
        }
        whf[kt] = fr;
    }
    const int junit = 16 * wave + l15;   // GRU unit this lane owns
    const float brz_r = b_ih[junit] + b_hh[junit];
    const float brz_z = b_ih[HH + junit] + b_hh[HH + junit];
    const float bn_i  = b_ih[2 * HH + junit];
    const float bn_h  = b_hh[2 * HH + junit];
    const float bh_reg = (wave < 3 && tcol < TT) ? bh[tcol] : 0.f;
    const float bo0 = bo[0];

    __syncthreads();

    // ---- precompute lin_signal[bb][f][t] = bs[t] + sum_t' seq[bb][t'][f] * Ws[t][t'] ----
    for (int idx = tid; idx < BB * FF * TT; idx += BLOCK) {
        int bb = idx / (FF * TT);
        int r  = idx - bb * (FF * TT);
        int f  = r / TT;
        int t  = r - f * TT;
        float acc = bs_lds[t];
#pragma unroll 4
        for (int tp = 0; tp < TT; ++tp)
            acc += bf2f(seq_lds[bb][tp * FF + f]) * Ws_lds[t][tp];
        sig_lds[bb][f * TT + t] = f2bf(acc);
    }

    float h_prev[4]  = {0.f, 0.f, 0.f, 0.f};
    float out_acc[4] = {0.f, 0.f, 0.f, 0.f};

    __syncthreads();

    for (int t = 0; t < TT; ++t) {
        // ---- load h A-fragments (swizzled ds_read_b128) ----
        bf16x8 ha[4];
        {
            const unsigned rowbyte = (unsigned)(l15 * 256);
            const unsigned swz = (unsigned)((l15 & 7) << 4);
#pragma unroll
            for (int kt = 0; kt < 4; ++kt) {
                unsigned kbyte = (unsigned)(kt * 64 + l4 * 16) ^ swz;
                ha[kt] = *(const bf16x8*)((const char*)h_lds + rowbyte + kbyte);
            }
        }
        // ---- lin_h = h @ Wh.T + bh  (waves 0-2) ----
        if (wave < 3) {
            f32x4 acc = {0.f, 0.f, 0.f, 0.f};
#pragma unroll
            for (int kt = 0; kt < 4; ++kt) acc = mfma16(ha[kt], whf[kt], acc);
#pragma unroll
            for (int r = 0; r < 4; ++r)
                linh_lds[l4 * 4 + r][tcol] = acc[r] + bh_reg;
        }
        // ---- gh = h @ W_hh.T (all waves, own 16-unit slice x 3 gates) ----
        f32x4 acc_r = {0.f,0.f,0.f,0.f}, acc_z = {0.f,0.f,0.f,0.f}, acc_ngh = {0.f,0.f,0.f,0.f};
#pragma unroll
        for (int kt = 0; kt < 4; ++kt) {
            acc_r   = mfma16(ha[kt], whh[0][kt], acc_r);
            acc_z   = mfma16(ha[kt], whh[1][kt], acc_z);
            acc_ngh = mfma16(ha[kt], whh[2][kt], acc_ngh);
        }
        __syncthreads();   // linh_lds visible

        // ---- attention scores e[bb][f] ----
        if (tid < BB * FF) {
            int bb = tid / FF, f = tid - bb * FF;
            float acc = bo0;
#pragma unroll 4
            for (int tp = 0; tp < TT; ++tp) {
                float s = linh_lds[bb][tp] + bf2f(sig_lds[bb][f * TT + tp]);
                acc += wo_lds[tp] * tanh_fast(s);
            }
            e_lds[bb][f] = acc;
        }
        __syncthreads();   // e visible

        // ---- softmax over F + scale x_t ----
        if (tid < BB) {
            int bb = tid;
            float m = -1e30f;
#pragma unroll
            for (int f = 0; f < FF; ++f) m = fmaxf(m, e_lds[bb][f]);
            float ex[FF], s = 0.f;
#pragma unroll
            for (int f = 0; f < FF; ++f) { ex[f] = __expf(e_lds[bb][f] - m); s += ex[f]; }
            float inv = 1.f / s;
#pragma unroll
            for (int f = 0; f < FF; ++f)
                x_lds[bb][f] = f2bf(ex[f] * inv * bf2f(seq_lds[bb][t * FF + f]));
        }
        __syncthreads();   // x visible

        // ---- gi = x @ W_ih.T ----
        bf16x8 xa = *(const bf16x8*)((const char*)x_lds + l15 * 64 + l4 * 16);
        acc_r = mfma16(xa, wih[0], acc_r);
        acc_z = mfma16(xa, wih[1], acc_z);
        f32x4 zero4 = {0.f, 0.f, 0.f, 0.f};
        f32x4 acc_ngi = mfma16(xa, wih[2], zero4);

        // ---- GRU elementwise; lane owns (bb = l4*4+r, unit = junit) ----
#pragma unroll
        for (int r = 0; r < 4; ++r) {
            int bb = l4 * 4 + r;
            float rg = sigmoid_fast(acc_r[r] + brz_r);
            float zg = sigmoid_fast(acc_z[r] + brz_z);
            float ng = tanh_fast(acc_ngi[r] + bn_i + rg * (acc_ngh[r] + bn_h));
            float hn = (1.f - zg) * ng + zg * h_prev[r];
            h_prev[r] = hn;
            out_acc[r] += hn * mask_lds[bb][t];
        }
        // ---- write h_new bf16 (swizzled) ----
#pragma unroll
        for (int r = 0; r < 4; ++r) {
            int bb = l4 * 4 + r;
            unsigned byte = ((unsigned)(2 * junit)) ^ (unsigned)((bb & 7) << 4);
            *(unsigned short*)((char*)h_lds + bb * 256 + byte) = f2bf(h_prev[r]);
        }
        __syncthreads();   // h_lds ready for next step
    }

    // ---- output ----
#pragma unroll
    for (int r = 0; r < 4; ++r) {
        int bb = l4 * 4 + r;
        out[(size_t)(bbase + bb) * HH + junit] = out_acc[r];
    }
}

extern "C" void kernel_launch(void* const* d_in, const int* in_sizes, int n_in,
                              void* d_out, int out_size, void* d_ws, size_t ws_size,
                              hipStream_t stream) {
    const float* seqs = (const float*)d_in[0];
    const float* mask = (const float*)d_in[1];
    const float* Wh   = (const float*)d_in[2];
    const float* bh   = (const float*)d_in[3];
    const float* Ws   = (const float*)d_in[4];
    const float* bs   = (const float*)d_in[5];
    const float* Wo   = (const float*)d_in[6];
    const float* bo   = (const float*)d_in[7];
    const float* W_ih = (const float*)d_in[8];
    const float* W_hh = (const float*)d_in[9];
    const float* b_ih = (const float*)d_in[10];
    const float* b_hh = (const float*)d_in[11];
    float* out = (float*)d_out;

    const int Btot = in_sizes[0] / (TT * FF);   // 16384
    const int grid = Btot / BB;                 // 1024
    enc_att_gru<<<grid, BLOCK, 0, stream>>>(seqs, mask, Wh, bh, Ws, bs, Wo, bo,
                                            W_ih, W_hh, b_ih, b_hh, out);
}

// Round 2
// 595.565 us; speedup vs baseline: 1.2394x; 1.2394x over previous
//
#include <hip/hip_runtime.h>
#include <hip/hip_bf16.h>

#define TT 36
#define FF 18
#define HH 128
#define BB 16
#define BLOCK 512
#define SIGP 40   // padded sig/linh row length (floats)

typedef __attribute__((ext_vector_type(4))) float f32x4;
typedef __attribute__((ext_vector_type(8))) short bf16x8;

#define L2E  1.4426950408889634f
#define L2E2 2.8853900817779268f

static __device__ __forceinline__ float bf2f(unsigned short u) {
    unsigned int x = ((unsigned int)u) << 16;
    return __builtin_bit_cast(float, x);
}
static __device__ __forceinline__ unsigned short f2bf(float f) {
    unsigned int x = __builtin_bit_cast(unsigned int, f);
    unsigned int r = (x + 0x7fffu + ((x >> 16) & 1u)) >> 16;
    return (unsigned short)r;
}
#if __has_builtin(__builtin_amdgcn_rcpf)
static __device__ __forceinline__ float frcp(float x) { return __builtin_amdgcn_rcpf(x); }
#else
static __device__ __forceinline__ float frcp(float x) { return 1.f / x; }
#endif
#if __has_builtin(__builtin_amdgcn_exp2f)
static __device__ __forceinline__ float fexp2(float x) { return __builtin_amdgcn_exp2f(x); }
#else
static __device__ __forceinline__ float fexp2(float x) { return __expf(x * 0.69314718056f); }
#endif
static __device__ __forceinline__ f32x4 mfma16(bf16x8 a, bf16x8 b, f32x4 c) {
    return __builtin_amdgcn_mfma_f32_16x16x32_bf16(a, b, c, 0, 0, 0);
}

__global__ __launch_bounds__(BLOCK, 4) void enc_att_gru(
    const float* __restrict__ seqs, const float* __restrict__ mask,
    const float* __restrict__ Wh,   const float* __restrict__ bh,
    const float* __restrict__ Ws,   const float* __restrict__ bs,
    const float* __restrict__ Wo,   const float* __restrict__ bo,
    const float* __restrict__ W_ih, const float* __restrict__ W_hh,
    const float* __restrict__ b_ih, const float* __restrict__ b_hh,
    float* __restrict__ out)
{
    __shared__ __align__(16) float sig2_lds[BB * FF * SIGP];   // 46080 B, pre-scaled by 2/ln2
    __shared__ float Ws2_lds[TT * TT];                         // [tp][t], pre-scaled
    __shared__ float bs2_lds[TT];
    __shared__ __align__(16) float wo2_lds[TT];                // -2*wo
    __shared__ __align__(16) float linh2_lds[BB][SIGP];        // pre-scaled lin_h
    __shared__ __align__(16) unsigned short h_lds[BB * HH];    // bf16, XOR-swizzled
    __shared__ __align__(16) unsigned short x_lds[BB][32];     // bf16, K padded to 32
    __shared__ float mask_lds[BB][TT];

    const int tid  = threadIdx.x;
    const int wave = tid >> 6;
    const int lane = tid & 63;
    const int l15  = lane & 15;
    const int l4   = lane >> 4;
    const int bbase = blockIdx.x * BB;
    const int bb2 = tid >> 5;      // e-phase batch row
    const int f2  = tid & 31;      // e-phase feature (valid < 18)

    // ---- stage small tensors ----
    for (int idx = tid; idx < TT * TT; idx += BLOCK) {
        int t = idx / TT, tp = idx - t * TT;
        Ws2_lds[tp * TT + t] = L2E2 * Ws[idx];      // transposed + scaled
    }
    if (tid < TT) { bs2_lds[tid] = L2E2 * bs[tid]; wo2_lds[tid] = -2.f * Wo[tid]; }
    for (int idx = tid; idx < BB * TT; idx += BLOCK) {
        int bb = idx / TT, t = idx - bb * TT;
        mask_lds[bb][t] = mask[(size_t)(bbase + bb) * TT + t];
    }
    for (int idx = tid; idx < BB * HH; idx += BLOCK) h_lds[idx] = 0;
    for (int idx = tid; idx < BB * 32; idx += BLOCK) ((unsigned short*)x_lds)[idx] = 0;
    __syncthreads();

    // ---- precompute sig2[bb][f][t] = (2/ln2)*(bs[t] + sum_tp seq[bb][tp][f]*Ws[t][tp]) ----
    if (f2 < FF) {
        const size_t sb = (size_t)(bbase + bb2) * (TT * FF) + f2;
        float* srow = &sig2_lds[(bb2 * FF + f2) * SIGP];
        for (int c = 0; c < 3; ++c) {              // t in chunks of 12 (register-friendly)
            float acc[12];
#pragma unroll
            for (int j = 0; j < 12; ++j) acc[j] = bs2_lds[c * 12 + j];
            for (int tp = 0; tp < TT; ++tp) {
                float s = seqs[sb + (size_t)tp * FF];
#pragma unroll
                for (int j = 0; j < 12; ++j)
                    acc[j] = fmaf(s, Ws2_lds[tp * TT + c * 12 + j], acc[j]);
            }
#pragma unroll
            for (int j = 0; j < 12; ++j) srow[c * 12 + j] = acc[j];
        }
    }

    // ---- persistent weight fragments (same self-consistent k-map as before) ----
    bf16x8 whh[3][4];
    for (int g = 0; g < 3; ++g)
        for (int kt = 0; kt < 4; ++kt) {
            const int o = g * HH + 16 * wave + l15;
            bf16x8 fr;
#pragma unroll
            for (int jj = 0; jj < 8; ++jj) {
                int k = kt * 32 + l4 * 8 + jj;
                fr[jj] = (short)f2bf(W_hh[(size_t)o * HH + k]);
            }
            whh[g][kt] = fr;
        }
    bf16x8 wih[3];
    for (int g = 0; g < 3; ++g) {
        const int o = g * HH + 16 * wave + l15;
        bf16x8 fr;
#pragma unroll
        for (int jj = 0; jj < 8; ++jj) {
            int f = l4 * 8 + jj;
            fr[jj] = (f < FF) ? (short)f2bf(W_ih[(size_t)o * FF + f]) : (short)0;
        }
        wih[g] = fr;
    }
    const int tcol = 16 * wave + l15;
    bf16x8 whf[4];
    for (int kt = 0; kt < 4; ++kt) {
        bf16x8 fr;
#pragma unroll
        for (int jj = 0; jj < 8; ++jj) {
            int k = kt * 32 + l4 * 8 + jj;
            fr[jj] = (wave < 3 && tcol < TT) ? (short)f2bf(Wh[(size_t)tcol * HH + k]) : (short)0;
        }
        whf[kt] = fr;
    }
    const int junit = 16 * wave + l15;
    const float brz_r = b_ih[junit] + b_hh[junit];
    const float brz_z = b_ih[HH + junit] + b_hh[HH + junit];
    const float bn_i  = b_ih[2 * HH + junit];
    const float bn_h  = b_hh[2 * HH + junit];
    const float bh_reg = (wave < 3 && tcol < TT) ? bh[tcol] : 0.f;
    float c0 = bo[0];
    for (int tp = 0; tp < TT; ++tp) c0 += Wo[tp];

    float seq_cur = (f2 < FF) ? seqs[(size_t)(bbase + bb2) * (TT * FF) + f2] : 0.f;

    float h_prev[4]  = {0.f, 0.f, 0.f, 0.f};
    float out_acc[4] = {0.f, 0.f, 0.f, 0.f};

    __syncthreads();

    for (int t = 0; t < TT; ++t) {
        // ---- Phase A: h fragments + lin_h MFMA + gh MFMA ----
        bf16x8 ha[4];
        {
            const unsigned rowbyte = (unsigned)(l15 * 256);
            const unsigned swz = (unsigned)((l15 & 7) << 4);
#pragma unroll
            for (int kt = 0; kt < 4; ++kt) {
                unsigned kbyte = (unsigned)(kt * 64 + l4 * 16) ^ swz;
                ha[kt] = *(const bf16x8*)((const char*)h_lds + rowbyte + kbyte);
            }
        }
        if (wave < 3) {
            f32x4 a = {0.f, 0.f, 0.f, 0.f};
#pragma unroll
            for (int kt = 0; kt < 4; ++kt) a = mfma16(ha[kt], whf[kt], a);
            if (tcol < TT) {
#pragma unroll
                for (int r = 0; r < 4; ++r)
                    linh2_lds[l4 * 4 + r][tcol] = (a[r] + bh_reg) * L2E2;
            }
        }
        f32x4 acc_r = {0.f,0.f,0.f,0.f}, acc_z = {0.f,0.f,0.f,0.f}, acc_n = {0.f,0.f,0.f,0.f};
#pragma unroll
        for (int kt = 0; kt < 4; ++kt) {
            acc_r = mfma16(ha[kt], whh[0][kt], acc_r);
            acc_z = mfma16(ha[kt], whh[1][kt], acc_z);
            acc_n = mfma16(ha[kt], whh[2][kt], acc_n);
        }
        __syncthreads();   // linh2 visible

        // ---- Phase B: e-scores (all 512 lanes) + in-register softmax + x ----
        {
            const int fs = (f2 < FF) ? f2 : (FF - 1);
            const float* srow = &sig2_lds[(bb2 * FF + fs) * SIGP];
            const float* lrow = &linh2_lds[bb2][0];
            float eacc = c0;
#pragma unroll
            for (int g = 0; g < 9; ++g) {
                f32x4 sv = *(const f32x4*)(srow + g * 4);
                f32x4 lv = *(const f32x4*)(lrow + g * 4);
                f32x4 wv = *(const f32x4*)(&wo2_lds[g * 4]);
#pragma unroll
                for (int j = 0; j < 4; ++j) {
                    float rr = frcp(1.f + fexp2(sv[j] + lv[j]));   // tanh = 1-2r folded into wo2
                    eacc = fmaf(wv[j], rr, eacc);
                }
            }
            float m = eacc;
            m = fmaxf(m, __shfl_xor(m, 1));
            m = fmaxf(m, __shfl_xor(m, 2));
            m = fmaxf(m, __shfl_xor(m, 4));
            m = fmaxf(m, __shfl_xor(m, 8));
            m = fmaxf(m, __shfl_xor(m, 16));
            float p = (f2 < FF) ? fexp2(L2E * (eacc - m)) : 0.f;
            float s = p;
            s += __shfl_xor(s, 1);
            s += __shfl_xor(s, 2);
            s += __shfl_xor(s, 4);
            s += __shfl_xor(s, 8);
            s += __shfl_xor(s, 16);
            float att = p * frcp(s);
            if (f2 < FF) {
                x_lds[bb2][f2] = f2bf(att * seq_cur);
                if (t + 1 < TT)
                    seq_cur = seqs[(size_t)(bbase + bb2) * (TT * FF) + (size_t)(t + 1) * FF + f2];
            }
        }
        __syncthreads();   // x visible

        // ---- Phase C: gi MFMA + GRU elementwise + h store ----
        bf16x8 xa = *(const bf16x8*)((const char*)x_lds + l15 * 64 + l4 * 16);
        acc_r = mfma16(xa, wih[0], acc_r);
        acc_z = mfma16(xa, wih[1], acc_z);
        f32x4 zero4 = {0.f, 0.f, 0.f, 0.f};
        f32x4 acc_gi = mfma16(xa, wih[2], zero4);
#pragma unroll
        for (int r = 0; r < 4; ++r) {
            int bb = l4 * 4 + r;
            float rg = frcp(1.f + fexp2(-L2E * (acc_r[r] + brz_r)));
            float zg = frcp(1.f + fexp2(-L2E * (acc_z[r] + brz_z)));
            float gin = acc_gi[r] + bn_i + rg * (acc_n[r] + bn_h);
            float ng = 1.f - 2.f * frcp(1.f + fexp2(L2E2 * gin));
            float hn = fmaf(zg, h_prev[r] - ng, ng);
            h_prev[r] = hn;
            out_acc[r] = fmaf(hn, mask_lds[bb][t], out_acc[r]);
            unsigned byte = ((unsigned)(2 * junit)) ^ (unsigned)((bb & 7) << 4);
            *(unsigned short*)((char*)h_lds + bb * 256 + byte) = f2bf(hn);
        }
        __syncthreads();   // h ready for next step
    }

#pragma unroll
    for (int r = 0; r < 4; ++r) {
        int bb = l4 * 4 + r;
        out[(size_t)(bbase + bb) * HH + junit] = out_acc[r];
    }
}

extern "C" void kernel_launch(void* const* d_in, const int* in_sizes, int n_in,
                              void* d_out, int out_size, void* d_ws, size_t ws_size,
                              hipStream_t stream) {
    const float* seqs = (const float*)d_in[0];
    const float* mask = (const float*)d_in[1];
    const float* Wh   = (const float*)d_in[2];
    const float* bh   = (const float*)d_in[3];
    const float* Ws   = (const float*)d_in[4];
    const float* bs   = (const float*)d_in[5];
    const float* Wo   = (const float*)d_in[6];
    const float* bo   = (const float*)d_in[7];
    const float* W_ih = (const float*)d_in[8];
    const float* W_hh = (const float*)d_in[9];
    const float* b_ih = (const float*)d_in[10];
    const float* b_hh = (const float*)d_in[11];
    float* out = (float*)d_out;

    const int Btot = in_sizes[0] / (TT * FF);   // 16384
    const int grid = Btot / BB;                 // 1024
    enc_att_gru<<<grid, BLOCK, 0, stream>>>(seqs, mask, Wh, bh, Ws, bs, Wo, bo,
                                            W_ih, W_hh, b_ih, b_hh, out);
}

// Round 3
// 384.053 us; speedup vs baseline: 1.9220x; 1.5507x over previous
//
#include <hip/hip_runtime.h>
#include <hip/hip_bf16.h>

#define TT 36
#define FF 18
#define HH 128
#define BB 16
#define BLOCK 512
#define SIGP 44   // padded sig/linh row length (floats); bank step 12 -> ~2-way

typedef __attribute__((ext_vector_type(4))) float f32x4;
typedef __attribute__((ext_vector_type(8))) short bf16x8;

#define L2E  1.4426950408889634f
#define L2E2 2.8853900817779268f

static __device__ __forceinline__ unsigned short f2bf(float f) {
    unsigned int x = __builtin_bit_cast(unsigned int, f);
    unsigned int r = (x + 0x7fffu + ((x >> 16) & 1u)) >> 16;
    return (unsigned short)r;
}
#if __has_builtin(__builtin_amdgcn_rcpf)
static __device__ __forceinline__ float frcp(float x) { return __builtin_amdgcn_rcpf(x); }
#else
static __device__ __forceinline__ float frcp(float x) { return 1.f / x; }
#endif
#if __has_builtin(__builtin_amdgcn_exp2f)
static __device__ __forceinline__ float fexp2(float x) { return __builtin_amdgcn_exp2f(x); }
#else
static __device__ __forceinline__ float fexp2(float x) { return __expf(x * 0.69314718056f); }
#endif
static __device__ __forceinline__ f32x4 mfma16(bf16x8 a, bf16x8 b, f32x4 c) {
    return __builtin_amdgcn_mfma_f32_16x16x32_bf16(a, b, c, 0, 0, 0);
}

__global__ __launch_bounds__(BLOCK, 2) void enc_att_gru(
    const float* __restrict__ seqs, const float* __restrict__ mask,
    const float* __restrict__ Wh,   const float* __restrict__ bh,
    const float* __restrict__ Ws,   const float* __restrict__ bs,
    const float* __restrict__ Wo,   const float* __restrict__ bo,
    const float* __restrict__ W_ih, const float* __restrict__ W_hh,
    const float* __restrict__ b_ih, const float* __restrict__ b_hh,
    float* __restrict__ out)
{
    __shared__ __align__(16) float sig2_lds[BB * FF * SIGP];   // pre-scaled by 2/ln2
    __shared__ float Ws2_lds[TT * TT];                         // [tp][t], pre-scaled
    __shared__ float bs2_lds[TT];
    __shared__ __align__(16) float wo2_lds[TT];                // -2*wo
    __shared__ __align__(16) float linh2_lds[BB][SIGP];        // pre-scaled lin_h
    // fragment-major: element (bb, k) lives at chunk = (k>>3)*BB + bb, slot k&7
    __shared__ __align__(16) unsigned short h_lds[16 * BB][8]; // k: 0..127
    __shared__ __align__(16) unsigned short x_lds[4 * BB][8];  // k: 0..31 (F padded)
    __shared__ float mask_lds[BB][TT];

    const int tid  = threadIdx.x;
    const int wave = tid >> 6;
    const int lane = tid & 63;
    const int l15  = lane & 15;
    const int l4   = lane >> 4;
    const int bbase = blockIdx.x * BB;
    const int bb2 = tid >> 5;      // e-phase batch row
    const int f2  = tid & 31;      // e-phase feature (valid < 18)

    // ---- stage small tensors ----
    for (int idx = tid; idx < TT * TT; idx += BLOCK) {
        int t = idx / TT, tp = idx - t * TT;
        Ws2_lds[tp * TT + t] = L2E2 * Ws[idx];      // transposed + scaled
    }
    if (tid < TT) { bs2_lds[tid] = L2E2 * bs[tid]; wo2_lds[tid] = -2.f * Wo[tid]; }
    for (int idx = tid; idx < BB * TT; idx += BLOCK) {
        int bb = idx / TT, t = idx - bb * TT;
        mask_lds[bb][t] = mask[(size_t)(bbase + bb) * TT + t];
    }
    for (int idx = tid; idx < 16 * BB * 8; idx += BLOCK) ((unsigned short*)h_lds)[idx] = 0;
    for (int idx = tid; idx < 4 * BB * 8; idx += BLOCK) ((unsigned short*)x_lds)[idx] = 0;
    __syncthreads();

    // ---- precompute sig2[bb][f][t] = (2/ln2)*(bs[t] + sum_tp seq[bb][tp][f]*Ws[t][tp]) ----
    if (f2 < FF) {
        const size_t sb = (size_t)(bbase + bb2) * (TT * FF) + f2;
        float* srow = &sig2_lds[(bb2 * FF + f2) * SIGP];
        for (int c = 0; c < 3; ++c) {              // t in chunks of 12
            float acc[12];
#pragma unroll
            for (int j = 0; j < 12; ++j) acc[j] = bs2_lds[c * 12 + j];
            for (int tp = 0; tp < TT; ++tp) {
                float s = seqs[sb + (size_t)tp * FF];
#pragma unroll
                for (int j = 0; j < 12; ++j)
                    acc[j] = fmaf(s, Ws2_lds[tp * TT + c * 12 + j], acc[j]);
            }
#pragma unroll
            for (int j = 0; j < 12; ++j) srow[c * 12 + j] = acc[j];
        }
    }

    // ---- persistent weight fragments (self-consistent k-map: k = kt*32 + l4*8 + j) ----
    bf16x8 whh[3][4];
    for (int g = 0; g < 3; ++g)
        for (int kt = 0; kt < 4; ++kt) {
            const int o = g * HH + 16 * wave + l15;
            bf16x8 fr;
#pragma unroll
            for (int jj = 0; jj < 8; ++jj) {
                int k = kt * 32 + l4 * 8 + jj;
                fr[jj] = (short)f2bf(W_hh[(size_t)o * HH + k]);
            }
            whh[g][kt] = fr;
        }
    bf16x8 wih[3];
    for (int g = 0; g < 3; ++g) {
        const int o = g * HH + 16 * wave + l15;
        bf16x8 fr;
#pragma unroll
        for (int jj = 0; jj < 8; ++jj) {
            int f = l4 * 8 + jj;
            fr[jj] = (f < FF) ? (short)f2bf(W_ih[(size_t)o * FF + f]) : (short)0;
        }
        wih[g] = fr;
    }
    const int tcol = 16 * wave + l15;
    bf16x8 whf[4];
    for (int kt = 0; kt < 4; ++kt) {
        bf16x8 fr;
#pragma unroll
        for (int jj = 0; jj < 8; ++jj) {
            int k = kt * 32 + l4 * 8 + jj;
            fr[jj] = (wave < 3 && tcol < TT) ? (short)f2bf(Wh[(size_t)tcol * HH + k]) : (short)0;
        }
        whf[kt] = fr;
    }
    const int junit = 16 * wave + l15;
    const float brz_r = b_ih[junit] + b_hh[junit];
    const float brz_z = b_ih[HH + junit] + b_hh[HH + junit];
    const float bn_i  = b_ih[2 * HH + junit];
    const float bn_h  = b_hh[2 * HH + junit];
    const float bh_reg = (wave < 3 && tcol < TT) ? bh[tcol] : 0.f;
    float c0 = bo[0];
    for (int tp = 0; tp < TT; ++tp) c0 += Wo[tp];

    float seq_cur = (f2 < FF) ? seqs[(size_t)(bbase + bb2) * (TT * FF) + f2] : 0.f;

    float h_prev[4]  = {0.f, 0.f, 0.f, 0.f};
    float out_acc[4] = {0.f, 0.f, 0.f, 0.f};

    __syncthreads();

    for (int t = 0; t < TT; ++t) {
        // ---- Phase A: h fragments (lane-linear, conflict-free) + lin_h + gh MFMAs ----
        bf16x8 ha[4];
#pragma unroll
        for (int kt = 0; kt < 4; ++kt)
            ha[kt] = *(const bf16x8*)(&h_lds[(kt * 4 + l4) * BB + l15][0]);
        if (wave < 3) {
            f32x4 a = {0.f, 0.f, 0.f, 0.f};
#pragma unroll
            for (int kt = 0; kt < 4; ++kt) a = mfma16(ha[kt], whf[kt], a);
            if (tcol < TT) {
#pragma unroll
                for (int r = 0; r < 4; ++r)
                    linh2_lds[l4 * 4 + r][tcol] = (a[r] + bh_reg) * L2E2;
            }
        }
        f32x4 acc_r = {0.f,0.f,0.f,0.f}, acc_z = {0.f,0.f,0.f,0.f}, acc_n = {0.f,0.f,0.f,0.f};
#pragma unroll
        for (int kt = 0; kt < 4; ++kt) {
            acc_r = mfma16(ha[kt], whh[0][kt], acc_r);
            acc_z = mfma16(ha[kt], whh[1][kt], acc_z);
            acc_n = mfma16(ha[kt], whh[2][kt], acc_n);
        }
        __syncthreads();   // linh2 visible

        // ---- Phase B: e-scores (all 512 lanes) + in-register softmax + x ----
        {
            const int fs = (f2 < FF) ? f2 : (FF - 1);
            const float* srow = &sig2_lds[(bb2 * FF + fs) * SIGP];
            const float* lrow = &linh2_lds[bb2][0];
            float eacc = c0;
#pragma unroll
            for (int g = 0; g < 9; ++g) {
                f32x4 sv = *(const f32x4*)(srow + g * 4);
                f32x4 lv = *(const f32x4*)(lrow + g * 4);
                f32x4 wv = *(const f32x4*)(&wo2_lds[g * 4]);
#pragma unroll
                for (int j = 0; j < 4; ++j) {
                    float rr = frcp(1.f + fexp2(sv[j] + lv[j]));   // tanh folded into wo2
                    eacc = fmaf(wv[j], rr, eacc);
                }
            }
            float m = eacc;
            m = fmaxf(m, __shfl_xor(m, 1));
            m = fmaxf(m, __shfl_xor(m, 2));
            m = fmaxf(m, __shfl_xor(m, 4));
            m = fmaxf(m, __shfl_xor(m, 8));
            m = fmaxf(m, __shfl_xor(m, 16));
            float p = (f2 < FF) ? fexp2(L2E * (eacc - m)) : 0.f;
            float s = p;
            s += __shfl_xor(s, 1);
            s += __shfl_xor(s, 2);
            s += __shfl_xor(s, 4);
            s += __shfl_xor(s, 8);
            s += __shfl_xor(s, 16);
            float att = p * frcp(s);
            if (f2 < FF) {
                x_lds[(f2 >> 3) * BB + bb2][f2 & 7] = f2bf(att * seq_cur);
                if (t + 1 < TT)
                    seq_cur = seqs[(size_t)(bbase + bb2) * (TT * FF) + (size_t)(t + 1) * FF + f2];
            }
        }
        __syncthreads();   // x visible

        // ---- Phase C: gi MFMA + GRU elementwise + h store ----
        bf16x8 xa = *(const bf16x8*)(&x_lds[l4 * BB + l15][0]);
        acc_r = mfma16(xa, wih[0], acc_r);
        acc_z = mfma16(xa, wih[1], acc_z);
        f32x4 zero4 = {0.f, 0.f, 0.f, 0.f};
        f32x4 acc_gi = mfma16(xa, wih[2], zero4);
#pragma unroll
        for (int r = 0; r < 4; ++r) {
            int bb = l4 * 4 + r;
            float rg = frcp(1.f + fexp2(-L2E * (acc_r[r] + brz_r)));
            float zg = frcp(1.f + fexp2(-L2E * (acc_z[r] + brz_z)));
            float gin = acc_gi[r] + bn_i + rg * (acc_n[r] + bn_h);
            float ng = 1.f - 2.f * frcp(1.f + fexp2(L2E2 * gin));
            float hn = fmaf(zg, h_prev[r] - ng, ng);
            h_prev[r] = hn;
            out_acc[r] = fmaf(hn, mask_lds[bb][t], out_acc[r]);
            h_lds[(2 * wave + (l15 >> 3)) * BB + bb][l15 & 7] = f2bf(hn);
        }
        __syncthreads();   // h ready for next step
    }

#pragma unroll
    for (int r = 0; r < 4; ++r) {
        int bb = l4 * 4 + r;
        out[(size_t)(bbase + bb) * HH + junit] = out_acc[r];
    }
}

extern "C" void kernel_launch(void* const* d_in, const int* in_sizes, int n_in,
                              void* d_out, int out_size, void* d_ws, size_t ws_size,
                              hipStream_t stream) {
    const float* seqs = (const float*)d_in[0];
    const float* mask = (const float*)d_in[1];
    const float* Wh   = (const float*)d_in[2];
    const float* bh   = (const float*)d_in[3];
    const float* Ws   = (const float*)d_in[4];
    const float* bs   = (const float*)d_in[5];
    const float* Wo   = (const float*)d_in[6];
    const float* bo   = (const float*)d_in[7];
    const float* W_ih = (const float*)d_in[8];
    const float* W_hh = (const float*)d_in[9];
    const float* b_ih = (const float*)d_in[10];
    const float* b_hh = (const float*)d_in[11];
    float* out = (float*)d_out;

    const int Btot = in_sizes[0] / (TT * FF);   // 16384
    const int grid = Btot / BB;                 // 1024
    enc_att_gru<<<grid, BLOCK, 0, stream>>>(seqs, mask, Wh, bh, Ws, bs, Wo, bo,
                                            W_ih, W_hh, b_ih, b_hh, out);
}